// Round 1
// baseline (834.333 us; speedup 1.0000x reference)
//
#include <hip/hip_runtime.h>
#include <hip/hip_bf16.h>

// Problem constants (from reference setup_inputs)
#define TDATA 100000
#define NE 500
#define NI 200
#define SUB 20
#define NB 3
#define TSYN 201

// Derived layout constants
#define TCAP 100352          // 49 * 2048 : conv t-coverage
#define SROW 100552          // 200 (front zero pad for tau<0) + TCAP, per-row stride of inT
#define HROW 216             // zero-padded taps: k in [-8, 207] stored at [k+8]
#define OFF_INT 8640         // float offset of inT in ws (after hpad = 2*20*216)

// ---------------------------------------------------------------------------
// Kernel 1: build zero-padded alpha-function tap bank
//   hp[(c*SUB+s)*HROW + (k+8)] = sum_b K_syn[s,b,c] * tt*exp(-tt),
//   tt = max(k - delta[s,c], 0) / exp(tau[b,c]);  zero outside k in [0,200]
// ---------------------------------------------------------------------------
__global__ __launch_bounds__(256) void hpad_kernel(
    const float* __restrict__ K_syn, const float* __restrict__ tau_syn,
    const float* __restrict__ delta_syn, float* __restrict__ hp)
{
    int idx = blockIdx.x * 256 + threadIdx.x;
    if (idx >= 2 * SUB * HROW) return;
    int c = idx / (SUB * HROW);
    int rem = idx - c * (SUB * HROW);
    int s = rem / HROW;
    int j = rem - s * HROW;
    int k = j - 8;
    float v = 0.f;
    if (k >= 0 && k < TSYN) {
        float ts = (float)k - delta_syn[s * 2 + c];
        ts = ts < 0.f ? 0.f : ts;
        #pragma unroll
        for (int b = 0; b < NB; b++) {
            float tau = expf(tau_syn[b * 2 + c]);
            float tt = ts / tau;
            v += K_syn[(s * NB + b) * 2 + c] * tt * expf(-tt);
        }
    }
    hp[idx] = v;
}

// ---------------------------------------------------------------------------
// Kernel 2: zero the front pad [0,200) and tail pad [200+TDATA, SROW) of each
// of the 40 inT rows (so conv window reads are exact zeros there).
// ---------------------------------------------------------------------------
__global__ __launch_bounds__(256) void padzero_kernel(float* __restrict__ inT)
{
    const int PERROW = 552;  // 200 front + 352 tail
    int idx = blockIdx.x * 256 + threadIdx.x;
    if (idx >= 40 * PERROW) return;
    int row = idx / PERROW;
    int e = idx - row * PERROW;
    int off = (e < 200) ? e : (200 + TDATA + (e - 200));
    inT[(long)row * SROW + off] = 0.f;
}

// ---------------------------------------------------------------------------
// Kernel 3: tall-skinny GEMM  inT[s][200+t] = sum_k S[t,k] * C[s,k]
// Block: 256 threads = 256 rows; K staged in LDS 32 at a time (stride 33:
// read bank = (tid+k)%32 -> conflict-free). C indexed uniformly -> s_load.
// Output written transposed (coalesced: lane = t).
// ---------------------------------------------------------------------------
__global__ __launch_bounds__(256) void gemm_kernel(
    const float* __restrict__ S, const float* __restrict__ C,
    float* __restrict__ outT, int K)
{
    __shared__ float tile[256 * 33];
    int tid = threadIdx.x;
    long r0 = (long)blockIdx.x * 256;
    float acc[SUB];
    #pragma unroll
    for (int s = 0; s < SUB; s++) acc[s] = 0.f;

    int rowL = tid >> 3;          // 0..31
    int kkL  = (tid & 7) << 2;    // 0,4,...,28

    for (int k0 = 0; k0 < K; k0 += 32) {
        int kt = K - k0; if (kt > 32) kt = 32;
        if (kt == 32) {
            #pragma unroll
            for (int p = 0; p < 8; p++) {
                int r = p * 32 + rowL;
                long rg = r0 + r;
                float4 v = make_float4(0.f, 0.f, 0.f, 0.f);
                if (rg < TDATA) v = *(const float4*)(S + rg * (long)K + k0 + kkL);
                float* tp = &tile[r * 33 + kkL];
                tp[0] = v.x; tp[1] = v.y; tp[2] = v.z; tp[3] = v.w;
            }
        } else {
            for (int p = 0; p < 8; p++) {
                int r = p * 32 + rowL;
                long rg = r0 + r;
                #pragma unroll
                for (int q = 0; q < 4; q++) {
                    int kk = kkL + q;
                    float v = 0.f;
                    if (rg < TDATA && kk < kt) v = S[rg * (long)K + k0 + kk];
                    tile[r * 33 + kk] = v;
                }
            }
        }
        __syncthreads();
        #pragma unroll 4
        for (int k = 0; k < kt; k++) {
            float sv = tile[tid * 33 + k];
            #pragma unroll
            for (int s = 0; s < SUB; s++)
                acc[s] += C[s * K + k0 + k] * sv;   // uniform index -> scalar load
        }
        __syncthreads();
    }

    long r = r0 + tid;
    if (r < TDATA) {
        #pragma unroll
        for (int s = 0; s < SUB; s++)
            outT[(long)s * SROW + 200 + r] = acc[s];
    }
}

// ---------------------------------------------------------------------------
// Kernel 4: causal FIR, 201 taps, per (s, c) channel; sums e and i branches.
// Thread computes 8 consecutive t's; window read as float4 from global
// (L1/L2-resident); taps are block-uniform -> scalar loads; zero-padded taps
// remove all edge branches.
// ---------------------------------------------------------------------------
__global__ __launch_bounds__(256) void conv_kernel(
    const float* __restrict__ inT, const float* __restrict__ hp,
    float* __restrict__ out)
{
    int s = blockIdx.y;
    long t0 = (long)blockIdx.x * 2048 + (long)threadIdx.x * 8;
    float acc[8];
    #pragma unroll
    for (int r = 0; r < 8; r++) acc[r] = 0.f;

    #pragma unroll
    for (int c = 0; c < 2; c++) {
        const float* w = inT + (long)(c * SUB + s) * SROW + 200 + t0; // tau=0 here
        const float* h = hp + (c * SUB + s) * HROW + 8;               // h[k]
        for (int jj = 0; jj < 208; jj += 4) {
            float4 x = *(const float4*)(w - 200 + jj);  // tau = t0-200+jj .. +3
            #pragma unroll
            for (int m = 0; m < 4; m++) {
                float xv = (m == 0) ? x.x : (m == 1) ? x.y : (m == 2) ? x.z : x.w;
                #pragma unroll
                for (int r = 0; r < 8; r++)
                    acc[r] += h[r + 200 - jj - m] * xv;  // uniform -> s_load, CSE'd
            }
        }
    }

    #pragma unroll
    for (int r = 0; r < 8; r++) {
        long t = t0 + r;
        if (t < TDATA) out[t * SUB + s] = acc[r];
    }
}

// ---------------------------------------------------------------------------
extern "C" void kernel_launch(void* const* d_in, const int* in_sizes, int n_in,
                              void* d_out, int out_size, void* d_ws, size_t ws_size,
                              hipStream_t stream)
{
    const float* S_e      = (const float*)d_in[0];
    const float* S_i      = (const float*)d_in[1];
    const float* C_e      = (const float*)d_in[2];
    const float* C_i      = (const float*)d_in[3];
    const float* K_syn    = (const float*)d_in[4];
    const float* tau_syn  = (const float*)d_in[5];
    const float* delta    = (const float*)d_in[6];
    float* out = (float*)d_out;
    float* ws  = (float*)d_ws;

    float* hp  = ws;               // 8640 floats
    float* inT = ws + OFF_INT;     // 40 rows x SROW floats (~16.1 MB)

    hipLaunchKernelGGL(hpad_kernel,    dim3(34),      dim3(256), 0, stream,
                       K_syn, tau_syn, delta, hp);
    hipLaunchKernelGGL(padzero_kernel, dim3(87),      dim3(256), 0, stream, inT);
    hipLaunchKernelGGL(gemm_kernel,    dim3(391),     dim3(256), 0, stream,
                       S_e, C_e, inT, NE);
    hipLaunchKernelGGL(gemm_kernel,    dim3(391),     dim3(256), 0, stream,
                       S_i, C_i, inT + (long)SUB * SROW, NI);
    hipLaunchKernelGGL(conv_kernel,    dim3(49, SUB), dim3(256), 0, stream,
                       inT, hp, out);
}

// Round 2
// 573.231 us; speedup vs baseline: 1.4555x; 1.4555x over previous
//
#include <hip/hip_runtime.h>
#include <hip/hip_bf16.h>

// Problem constants
#define TDATA 100000
#define NE 500
#define NI 200
#define SUB 20
#define NB 3
#define TSYN 201

// Layout constants
#define TCAP 100352          // 49 * 2048 conv coverage
#define SROW 100552          // 200 front pad + TCAP
#define HROW 216             // taps padded: k in [-8,207] at [k+8]
#define KTE 16               // ceil(500/32) k-tiles (e)
#define KTI 7                // ceil(200/32) k-tiles (i)
// ws float offsets
#define OFF_HP   0
#define OFF_CTE  8640                    // hp = 2*20*216 = 8640
#define OFF_CTI  (OFF_CTE + KTE*32*32)   // 8640 + 16384 = 25024
#define OFF_INT  (OFF_CTI + KTI*32*32)   // 25024 + 7168 = 32192

// ---------------------------------------------------------------------------
// Fused setup: taps + pad-zeroing + C transposes. One dispatch.
//   idx ranges: [0,8640) hp | [8640,30720) inT pads | [30720,47104) Ct_e |
//               [47104,54272) Ct_i.  Grid = 212*256 = 54272 exactly.
// ---------------------------------------------------------------------------
__global__ __launch_bounds__(256) void setup_kernel(
    const float* __restrict__ C_e, const float* __restrict__ C_i,
    const float* __restrict__ K_syn, const float* __restrict__ tau_syn,
    const float* __restrict__ delta_syn, float* __restrict__ ws)
{
    int idx = blockIdx.x * 256 + threadIdx.x;
    if (idx < 8640) {                       // ---- taps
        int c = idx / (SUB * HROW);
        int rem = idx - c * (SUB * HROW);
        int s = rem / HROW;
        int k = (rem - s * HROW) - 8;
        float v = 0.f;
        if (k >= 0 && k < TSYN) {
            float ts = (float)k - delta_syn[s * 2 + c];
            ts = ts < 0.f ? 0.f : ts;
            #pragma unroll
            for (int b = 0; b < NB; b++) {
                float tt = ts / expf(tau_syn[b * 2 + c]);
                v += K_syn[(s * NB + b) * 2 + c] * tt * expf(-tt);
            }
        }
        ws[OFF_HP + idx] = v;
    } else if (idx < 30720) {               // ---- inT front/tail pad zeros
        int j = idx - 8640;
        const int PERROW = 552;             // 200 front + 352 tail
        int row = j / PERROW;
        int e = j - row * PERROW;
        int off = (e < 200) ? e : (200 + TDATA + (e - 200));
        ws[OFF_INT + (long)row * SROW + off] = 0.f;
    } else if (idx < 47104) {               // ---- Ct_e[k][32]
        int j = idx - 30720;
        int k = j >> 5, s = j & 31;
        ws[OFF_CTE + j] = (s < SUB && k < NE) ? C_e[s * NE + k] : 0.f;
    } else {                                // ---- Ct_i[k][32]
        int j = idx - 47104;
        int k = j >> 5, s = j & 31;
        ws[OFF_CTI + j] = (s < SUB && k < NI) ? C_i[s * NI + k] : 0.f;
    }
}

// ---------------------------------------------------------------------------
// Fused tall-skinny GEMM (e and i in one grid): inT[s][200+t] = sum_k S[t,k]*C[s,k]
// 256 threads = 256 rows; 32-wide k-tiles staged in LDS (stride 33 ->
// conflict-free reads); register-prefetch pipeline hides HBM latency behind
// the 640-FMA compute phase; Ct rows are contiguous -> s_load_dwordx8.
// Blocks [0,391) -> e-GEMM, [391,782) -> i-GEMM.
// ---------------------------------------------------------------------------
__global__ __launch_bounds__(256) void gemm_kernel(
    const float* __restrict__ Se, const float* __restrict__ Si,
    float* __restrict__ ws)
{
    __shared__ float tile[256 * 33];
    const int tid = threadIdx.x;
    const bool isE = blockIdx.x < 391;
    const float* S  = isE ? Se : Si;
    const float* Ct = ws + (isE ? OFF_CTE : OFF_CTI);
    const int K     = isE ? NE : NI;
    const int TILES = isE ? KTE : KTI;
    const long r0   = (long)(isE ? blockIdx.x : blockIdx.x - 391) * 256;
    float* orow = ws + OFF_INT + (isE ? 0 : (long)SUB * SROW);

    const int rowL = tid >> 3;          // 0..31
    const int kkL  = (tid & 7) << 2;    // 0,4,...,28

    float4 pre[8];
    auto stage = [&](int k0) {
        #pragma unroll
        for (int p = 0; p < 8; p++) {
            long rg = r0 + p * 32 + rowL;
            float4 v = make_float4(0.f, 0.f, 0.f, 0.f);
            if (rg < TDATA && k0 + kkL + 4 <= K)
                v = *(const float4*)(S + rg * (long)K + k0 + kkL);
            pre[p] = v;
        }
    };
    auto commit = [&]() {
        #pragma unroll
        for (int p = 0; p < 8; p++) {
            float* tp = &tile[(p * 32 + rowL) * 33 + kkL];
            tp[0] = pre[p].x; tp[1] = pre[p].y; tp[2] = pre[p].z; tp[3] = pre[p].w;
        }
    };

    float acc[SUB];
    #pragma unroll
    for (int s = 0; s < SUB; s++) acc[s] = 0.f;

    stage(0);
    commit();
    __syncthreads();

    for (int t = 0; t < TILES; t++) {
        if (t + 1 < TILES) stage((t + 1) * 32);     // loads in flight over compute
        const float* crow = Ct + t * 32 * 32;
        #pragma unroll
        for (int k = 0; k < 32; k++) {
            float sv = tile[tid * 33 + k];
            #pragma unroll
            for (int s = 0; s < SUB; s++)
                acc[s] += crow[k * 32 + s] * sv;    // uniform -> s_load_dwordx8
        }
        __syncthreads();
        if (t + 1 < TILES) commit();
        __syncthreads();
    }

    long r = r0 + tid;
    if (r < TDATA) {
        #pragma unroll
        for (int s = 0; s < SUB; s++)
            orow[(long)s * SROW + 200 + r] = acc[s];
    }
}

// ---------------------------------------------------------------------------
// Causal 201-tap FIR per (s,c), summing e+i. Thread = 8 consecutive t's;
// window float4 from global (L1-resident); taps block-uniform -> s_load;
// zero-padded taps/window remove edge branches.
// ---------------------------------------------------------------------------
__global__ __launch_bounds__(256) void conv_kernel(
    const float* __restrict__ ws, float* __restrict__ out)
{
    const float* inT = ws + OFF_INT;
    const float* hp  = ws + OFF_HP;
    int s = blockIdx.y;
    long t0 = (long)blockIdx.x * 2048 + (long)threadIdx.x * 8;
    float acc[8];
    #pragma unroll
    for (int r = 0; r < 8; r++) acc[r] = 0.f;

    #pragma unroll
    for (int c = 0; c < 2; c++) {
        const float* w = inT + (long)(c * SUB + s) * SROW + 200 + t0;
        const float* h = hp + (c * SUB + s) * HROW + 8;
        #pragma unroll 4
        for (int jj = 0; jj < 208; jj += 4) {
            float4 x = *(const float4*)(w - 200 + jj);
            #pragma unroll
            for (int m = 0; m < 4; m++) {
                float xv = (m == 0) ? x.x : (m == 1) ? x.y : (m == 2) ? x.z : x.w;
                #pragma unroll
                for (int r = 0; r < 8; r++)
                    acc[r] += h[r + 200 - jj - m] * xv;
            }
        }
    }

    #pragma unroll
    for (int r = 0; r < 8; r++) {
        long t = t0 + r;
        if (t < TDATA) out[t * SUB + s] = acc[r];
    }
}

// ---------------------------------------------------------------------------
extern "C" void kernel_launch(void* const* d_in, const int* in_sizes, int n_in,
                              void* d_out, int out_size, void* d_ws, size_t ws_size,
                              hipStream_t stream)
{
    const float* S_e     = (const float*)d_in[0];
    const float* S_i     = (const float*)d_in[1];
    const float* C_e     = (const float*)d_in[2];
    const float* C_i     = (const float*)d_in[3];
    const float* K_syn   = (const float*)d_in[4];
    const float* tau_syn = (const float*)d_in[5];
    const float* delta   = (const float*)d_in[6];
    float* out = (float*)d_out;
    float* ws  = (float*)d_ws;

    hipLaunchKernelGGL(setup_kernel, dim3(212),     dim3(256), 0, stream,
                       C_e, C_i, K_syn, tau_syn, delta, ws);
    hipLaunchKernelGGL(gemm_kernel,  dim3(782),     dim3(256), 0, stream,
                       S_e, S_i, ws);
    hipLaunchKernelGGL(conv_kernel,  dim3(49, SUB), dim3(256), 0, stream,
                       ws, out);
}

// Round 3
// 409.495 us; speedup vs baseline: 2.0375x; 1.3998x over previous
//
#include <hip/hip_runtime.h>
#include <hip/hip_bf16.h>

// Problem constants
#define TDATA 100000
#define NE 500
#define NI 200
#define SUB 20
#define NB 3
#define TSYN 201

// Layout
#define SROW 100552              // 200 front pad + data + tail pad (49*2048+200+...)
#define HROW 216                 // conv taps padded: k in [-8,207] at [k+8]
#define STEPS_E 32               // K padded to 512 (31 full + 1 peel)
#define STEPS_I 13               // K padded to 208 (12 full + 1 peel)
#define FULL_E 31
#define FULL_I 12
#define GEMM_BLKS 782            // ceil(100000/128) row-tiles per matrix

// ws float offsets
#define OFF_HP  0                            // 2*20*216 = 8640 floats
#define OFF_BE  8640                         // e A-frags: 32*64*8 bf16 = 8192 float slots
#define OFF_BI  (OFF_BE + 8192)              // 16832; i A-frags: 13*64*8 bf16 = 3328 slots
#define OFF_INT (OFF_BI + 3328)              // 20160 (16B-aligned), inT = 40 rows x SROW

typedef __bf16 bf16x8 __attribute__((ext_vector_type(8)));
typedef float  f32x16 __attribute__((ext_vector_type(16)));

// ---------------------------------------------------------------------------
// Setup: conv taps | inT pad zeros | bf16 A-operand fragments (exact MFMA
// per-lane order: element j of lane l, k-step u  ->  C[s=l&31][k=16u+8*(l>>5)+j])
// Grid = 210*256 = 53760 exactly.
// ---------------------------------------------------------------------------
__global__ __launch_bounds__(256) void setup_kernel(
    const float* __restrict__ C_e, const float* __restrict__ C_i,
    const float* __restrict__ K_syn, const float* __restrict__ tau_syn,
    const float* __restrict__ delta_syn, float* __restrict__ ws)
{
    int idx = blockIdx.x * 256 + threadIdx.x;
    if (idx < 8640) {                        // ---- conv taps (zero-padded)
        int c = idx / (SUB * HROW);
        int rem = idx - c * (SUB * HROW);
        int s = rem / HROW;
        int k = (rem - s * HROW) - 8;
        float v = 0.f;
        if (k >= 0 && k < TSYN) {
            float ts = (float)k - delta_syn[s * 2 + c];
            ts = ts < 0.f ? 0.f : ts;
            #pragma unroll
            for (int b = 0; b < NB; b++) {
                float tt = ts / expf(tau_syn[b * 2 + c]);
                v += K_syn[(s * NB + b) * 2 + c] * tt * expf(-tt);
            }
        }
        ws[OFF_HP + idx] = v;
    } else if (idx < 30720) {                // ---- inT front/tail pad zeros
        int j = idx - 8640;
        const int PERROW = 552;              // 200 front + 352 tail
        int row = j / PERROW;
        int e = j - row * PERROW;
        int off = (e < 200) ? e : (200 + TDATA + (e - 200));
        ws[OFF_INT + (long)row * SROW + off] = 0.f;
    } else if (idx < 47104) {                // ---- e A-frags (bf16)
        int j = idx - 30720;                 // 32*64*8 = 16384
        int step = j >> 9;
        int lane = (j >> 3) & 63;
        int jj = j & 7;
        int k = step * 16 + ((lane >> 5) << 3) + jj;
        int s = lane & 31;
        float v = (s < SUB && k < NE) ? C_e[s * NE + k] : 0.f;
        ((__hip_bfloat16*)(ws + OFF_BE))[j] = (__hip_bfloat16)v;
    } else {                                 // ---- i A-frags (bf16)
        int j = idx - 47104;                 // 13*64*8 = 6656
        int step = j >> 9;
        int lane = (j >> 3) & 63;
        int jj = j & 7;
        int k = step * 16 + ((lane >> 5) << 3) + jj;
        int s = lane & 31;
        float v = (s < SUB && k < NI) ? C_i[s * NI + k] : 0.f;
        ((__hip_bfloat16*)(ws + OFF_BI))[j] = (__hip_bfloat16)v;
    }
}

// ---------------------------------------------------------------------------
// MFMA GEMM: wave = one 32-row tile, all 20 cols, full K. No LDS, no barriers,
// no s_load in the hot loop -> pure vmcnt pipeline at 24 waves/CU.
//   A (taps)  : pre-packed frags, coalesced 16B/lane, L1/L2-resident
//   B (S rows): lane n=l&31 -> row, half h=l>>5 -> k+8h; 2 float4 + cvt bf16
//   D[m=s][n=row]: verified layout col=lane&31, row=(reg&3)+8*(reg>>2)+4*h
// ---------------------------------------------------------------------------
template<int K, int FULL>
__device__ __forceinline__ void gemm_body(
    const float* __restrict__ S, const float* __restrict__ wsA,
    float* __restrict__ inT, long row0, int lane)
{
    const int n = lane & 31, h = lane >> 5;
    long row = row0 + n; if (row >= TDATA) row = TDATA - 1;
    const float* rp = S + row * (long)K + h * 8;
    const bf16x8* afr = (const bf16x8*)wsA;
    f32x16 acc = {};

    #pragma unroll 4
    for (int u = 0; u < FULL; u++) {
        float4 lo = *(const float4*)(rp + 16 * u);
        float4 hi = *(const float4*)(rp + 16 * u + 4);
        bf16x8 b;
        b[0] = (__bf16)lo.x; b[1] = (__bf16)lo.y; b[2] = (__bf16)lo.z; b[3] = (__bf16)lo.w;
        b[4] = (__bf16)hi.x; b[5] = (__bf16)hi.y; b[6] = (__bf16)hi.z; b[7] = (__bf16)hi.w;
        bf16x8 a = afr[u * 64 + lane];
        acc = __builtin_amdgcn_mfma_f32_32x32x16_bf16(a, b, acc, 0, 0, 0);
    }
    {   // peel: tail k-step, zero-fill past K (matching taps are zero too)
        int kb = FULL * 16 + h * 8;
        float4 lo = make_float4(0.f, 0.f, 0.f, 0.f);
        float4 hi = make_float4(0.f, 0.f, 0.f, 0.f);
        if (kb + 8 <= K) {
            lo = *(const float4*)(rp + 16 * FULL);
            hi = *(const float4*)(rp + 16 * FULL + 4);
        } else if (kb + 4 <= K) {
            lo = *(const float4*)(rp + 16 * FULL);
        }
        bf16x8 b;
        b[0] = (__bf16)lo.x; b[1] = (__bf16)lo.y; b[2] = (__bf16)lo.z; b[3] = (__bf16)lo.w;
        b[4] = (__bf16)hi.x; b[5] = (__bf16)hi.y; b[6] = (__bf16)hi.z; b[7] = (__bf16)hi.w;
        bf16x8 a = afr[FULL * 64 + lane];
        acc = __builtin_amdgcn_mfma_f32_32x32x16_bf16(a, b, acc, 0, 0, 0);
    }

    long t = row0 + n;                       // unclamped, guarded below
    #pragma unroll
    for (int r = 0; r < 16; r++) {
        int m = (r & 3) + 8 * (r >> 2) + 4 * h;
        if (m < SUB && t < TDATA)
            inT[(long)m * SROW + 200 + t] = acc[r];
    }
}

__global__ __launch_bounds__(256) void gemm_kernel(
    const float* __restrict__ Se, const float* __restrict__ Si,
    float* __restrict__ ws)
{
    int lane = threadIdx.x & 63, wave = threadIdx.x >> 6;
    if (blockIdx.x < GEMM_BLKS) {
        long row0 = (long)blockIdx.x * 128 + wave * 32;
        gemm_body<NE, FULL_E>(Se, ws + OFF_BE, ws + OFF_INT, row0, lane);
    } else {
        long row0 = (long)(blockIdx.x - GEMM_BLKS) * 128 + wave * 32;
        gemm_body<NI, FULL_I>(Si, ws + OFF_BI,
                              ws + OFF_INT + (long)SUB * SROW, row0, lane);
    }
}

// ---------------------------------------------------------------------------
// Conv: block = (s, 2048 t's); windows staged in LDS with i+(i>>5) swizzle
// (raw stride-8 lane pattern would be 16-way bank-conflicted); taps in LDS,
// broadcast ds_read_b128. Thread = 8 consecutive t's; 16-float reg window
// per 8-tap group -> 64 fmac per 16 LDS b32 reads. No s_load in loop.
// ---------------------------------------------------------------------------
#define SW(i) ((i) + ((i) >> 5))

__global__ __launch_bounds__(256) void conv_kernel(
    const float* __restrict__ ws, float* __restrict__ out)
{
    __shared__ __align__(16) float W[2][2336];   // SW(2255)=2325 max
    __shared__ __align__(16) float HT[2][208];
    const int tid = threadIdx.x;
    const int s = blockIdx.y;
    const long t0 = (long)blockIdx.x * 2048;

    // stage windows: W[c][q] = row_c[t0 - 208 + q], q in [0,2256)
    for (int i = tid; i < 1128; i += 256) {
        int c = i >= 564;
        int i4 = i - c * 564;
        float4 v = *(const float4*)(ws + OFF_INT + (long)(c * SUB + s) * SROW
                                    + t0 - 8 + 4 * i4);
        int b = 4 * i4;
        int p = SW(b);                        // contiguous within aligned-4 runs
        W[c][p] = v.x; W[c][p + 1] = v.y; W[c][p + 2] = v.z; W[c][p + 3] = v.w;
    }
    if (tid < 104) {                          // taps: 2 channels x 208
        int c = tid >= 52;
        int j4 = (tid - c * 52) * 4;
        *(float4*)&HT[c][j4] =
            *(const float4*)(ws + OFF_HP + (c * SUB + s) * HROW + 8 + j4);
    }
    __syncthreads();

    float acc[8];
    #pragma unroll
    for (int r = 0; r < 8; r++) acc[r] = 0.f;

    #pragma unroll
    for (int c = 0; c < 2; c++) {
        #pragma unroll 2
        for (int g = 0; g < 26; g++) {
            int k0 = g << 3;
            int xb = (tid << 3) + 200 - k0;
            float x[16];
            #pragma unroll
            for (int q = 0; q < 16; q++) x[q] = W[c][SW(xb + q)];
            float h[8];
            *(float4*)&h[0] = *(const float4*)&HT[c][k0];
            *(float4*)&h[4] = *(const float4*)&HT[c][k0 + 4];
            #pragma unroll
            for (int j = 0; j < 8; j++)
                #pragma unroll
                for (int r = 0; r < 8; r++)
                    acc[r] += h[j] * x[8 + r - j];
        }
    }

    #pragma unroll
    for (int r = 0; r < 8; r++) {
        long t = t0 + 8 * tid + r;
        if (t < TDATA) out[t * SUB + s] = acc[r];
    }
}

// ---------------------------------------------------------------------------
extern "C" void kernel_launch(void* const* d_in, const int* in_sizes, int n_in,
                              void* d_out, int out_size, void* d_ws, size_t ws_size,
                              hipStream_t stream)
{
    const float* S_e     = (const float*)d_in[0];
    const float* S_i     = (const float*)d_in[1];
    const float* C_e     = (const float*)d_in[2];
    const float* C_i     = (const float*)d_in[3];
    const float* K_syn   = (const float*)d_in[4];
    const float* tau_syn = (const float*)d_in[5];
    const float* delta   = (const float*)d_in[6];
    float* out = (float*)d_out;
    float* ws  = (float*)d_ws;

    hipLaunchKernelGGL(setup_kernel, dim3(210), dim3(256), 0, stream,
                       C_e, C_i, K_syn, tau_syn, delta, ws);
    hipLaunchKernelGGL(gemm_kernel, dim3(2 * GEMM_BLKS), dim3(256), 0, stream,
                       S_e, S_i, ws);
    hipLaunchKernelGGL(conv_kernel, dim3(49, SUB), dim3(256), 0, stream,
                       ws, out);
}